// Round 13
// baseline (182.587 us; speedup 1.0000x reference)
//
#include <hip/hip_runtime.h>
#include <hip/hip_bf16.h>

// ---------------------------------------------------------------------------
// TransformerPlanner: algebra-collapsed fused implementation.
//
// R13 = R12 (passed, k_main 64.0us) with ONE change:
//   __launch_bounds__(256,4) -> (256,5).
// Rationale: VGPR=60 permits 8 waves/SIMD and LDS=32256 permits 5 WGs/CU,
// but the old bound self-capped residency at 4. Latency-bound kernel
// (MfmaUtil 11%, VALU 43%, HBM <1%, ~46% idle) => resident waves are the
// remaining lever. Zero arithmetic change.
// ---------------------------------------------------------------------------

typedef __bf16 bf16x8 __attribute__((ext_vector_type(8)));
typedef float  f32x4  __attribute__((ext_vector_type(4)));
static_assert(sizeof(bf16x8) == 16, "bf16x8 must be 16B");

__device__ __forceinline__ unsigned short f2b(float x) {
  __bf16 h = (__bf16)x;
  return __builtin_bit_cast(unsigned short, h);
}
__device__ __forceinline__ float b2f(unsigned short u) {
  return (float)__builtin_bit_cast(__bf16, u);
}
__device__ __forceinline__ float dot4(float4 a, float4 b) {
  return a.x*b.x + a.y*b.y + a.z*b.z + a.w*b.w;
}
__device__ __forceinline__ f32x4 mfma16(bf16x8 a, bf16x8 b, f32x4 c) {
  return __builtin_amdgcn_mfma_f32_16x16x32_bf16(a, b, c, 0, 0, 0);
}

// Fragment-order offsets (ushort index) for B matrices:
// lane l of a (ntile,ktile) block holds n = ntile*16 + (l&15),
// k = ktile*32 + (l>>4)*8 .. +8. Block = 64 lanes x 8 ushort = 512.
__device__ __forceinline__ int om_off(int n, int k) {   // 128x192, 6 ktiles
  return (((n >> 4)*6 + (k >> 5))*64 + ((k >> 3) & 3)*16 + (n & 15))*8 + (k & 7);
}
__device__ __forceinline__ int w1_off(int n, int k) {   // 256x128, 4 ktiles
  return (((n >> 4)*4 + (k >> 5))*64 + ((k >> 3) & 3)*16 + (n & 15))*8 + (k & 7);
}
__device__ __forceinline__ int w2_off(int n, int k) {   // 128x256, 8 ktiles
  return (((n >> 4)*8 + (k >> 5))*64 + ((k >> 3) & 3)*16 + (n & 15))*8 + (k & 7);
}

// ---- workspace layout (byte offsets into d_ws) ----
#define WS_OM    0          // ushort[24576]  OM fragments (8 ntile x 6 ktile)
#define WS_FC1   49152      // ushort[32768]  fc1 fragments (16 x 4)
#define WS_FC2   114688     // ushort[32768]  fc2 fragments (8 x 8)
#define WS_QN    192000     // float[3*128]  LN'd queries
#define WS_SB    193536     // float[480]    Sb[w][h][t]
#define WS_SU    195456     // float[72]     Su[24],Sw[24],Sc[24]
#define WS_SCAL  195744     // float[3]      Suu,Sww,Suw
#define WS_SUB   195756     // float[20]
#define WS_SWB   195836     // float[20]
#define WS_SBB   195916     // float[20]

// ---------------------------------------------------------------------------
__device__ float mean128(float v, volatile float* red) {
  #pragma unroll
  for (int o = 32; o; o >>= 1) v += __shfl_down(v, o, 64);
  __syncthreads();
  if ((threadIdx.x & 63) == 0) red[threadIdx.x >> 6] = v;
  __syncthreads();
  return (red[0] + red[1]) * (1.0f / 128.0f);
}

// Merged prep kernel: 53 blocks x 128 threads. (unchanged, proven R7/R8/R12)
__global__ void k_prep(
    const float* __restrict__ coord_w, const float* __restrict__ coord_b,
    const float* __restrict__ pos_emb, const float* __restrict__ side_emb,
    const float* __restrict__ query_emb,
    const float* __restrict__ tln_g, const float* __restrict__ tln_b,
    const float* __restrict__ qln_g, const float* __restrict__ qln_b,
    const float* __restrict__ ipw, const float* __restrict__ ipb,
    const float* __restrict__ opw, const float* __restrict__ opb,
    const float* __restrict__ f1w, const float* __restrict__ f2w,
    char* __restrict__ ws)
{
  const int b = blockIdx.x, tid = threadIdx.x;   // 128 threads
  if (b >= 21) {
    if (b < 37) {
      unsigned short* dst = (unsigned short*)(ws + WS_FC1);
      int i0 = (b - 21)*2048;
      #pragma unroll
      for (int j = 0; j < 16; j++) {
        int i = i0 + j*128 + tid;
        dst[w1_off(i >> 7, i & 127)] = f2b(f1w[i]);
      }
    } else {
      unsigned short* dst = (unsigned short*)(ws + WS_FC2);
      int i0 = (b - 37)*2048;
      #pragma unroll
      for (int j = 0; j < 16; j++) {
        int i = i0 + j*128 + tid;
        dst[w2_off(i >> 8, i & 255)] = f2b(f2w[i]);
      }
    }
    return;
  }

  __shared__ float red[2];
  __shared__ float qn[3][128];
  __shared__ float qmat[3][128];
  __shared__ float vecA[128];
  __shared__ float vecB[128];
  __shared__ float vecC[128];
  __shared__ float kuA[128];
  __shared__ float kwA[128];
  __shared__ float kcA[128];
  const int d = tid;
  const int t = b;                // 0..19 = token blocks, 20 = misc
  unsigned short* OMw = (unsigned short*)(ws + WS_OM);

  float u  = coord_w[d*2+0];
  float w2 = coord_w[d*2+1];
  float g  = tln_g[d];
  float mu = mean128(u,  red);
  float mw = mean128(w2, red);
  float uh = u - mu, wh = w2 - mw;

  // LN(query_emb)
  #pragma unroll
  for (int w = 0; w < 3; w++) {
    float qe = query_emb[w*128 + d];
    float m  = mean128(qe, red);
    float m2 = mean128(qe*qe, red);
    float var = m2 - m*m;
    qn[w][d] = (qe - m) * rsqrtf(var + 1e-5f) * qln_g[d] + qln_b[d];
  }
  __syncthreads();
  // q = qn @ wq^T + bq
  {
    const float* wqr = ipw + d*128;
    float a0 = 0, a1 = 0, a2 = 0;
    for (int k4 = 0; k4 < 32; k4++) {
      float4 wv4 = *(const float4*)&wqr[k4*4];
      a0 += dot4(wv4, *(const float4*)&qn[0][k4*4]);
      a1 += dot4(wv4, *(const float4*)&qn[1][k4*4]);
      a2 += dot4(wv4, *(const float4*)&qn[2][k4*4]);
    }
    float bq = ipb[d];
    qmat[0][d] = a0 + bq; qmat[1][d] = a1 + bq; qmat[2][d] = a2 + bq;
  }
  __syncthreads();

  if (t < 20) {
    float base = coord_b[d] + pos_emb[(t % 10)*128 + d] + side_emb[(t < 10 ? 0 : 1)*128 + d];
    float mb = mean128(base, red);
    float bh = base - mb;
    float sub = mean128(uh*bh, red);
    float swb = mean128(wh*bh, red);
    float sbb = mean128(bh*bh, red);
    if (d == 0) {
      ((float*)(ws + WS_SUB))[t] = sub;
      ((float*)(ws + WS_SWB))[t] = swb;
      ((float*)(ws + WS_SBB))[t] = sbb;
    }
    vecA[d] = bh * g;
    __syncthreads();
    const float* wkr = ipw + (128 + d)*128;
    const float* wvr = ipw + (256 + d)*128;
    float kb = 0, vb = 0;
    for (int k4 = 0; k4 < 32; k4++) {
      float4 a4 = *(const float4*)&vecA[k4*4];
      kb += dot4(*(const float4*)&wkr[k4*4], a4);
      vb += dot4(*(const float4*)&wvr[k4*4], a4);
    }
    kuA[d] = kb;
    vecB[d] = vb;
    __syncthreads();
    if (d < 24) {
      int w = d / 8, h = d % 8;
      float s = 0;
      #pragma unroll
      for (int dl = 0; dl < 16; dl++) s += qmat[w][h*16 + dl] * kuA[h*16 + dl];
      ((float*)(ws + WS_SB))[(w*8 + h)*20 + t] = 0.25f * s;
    }
    // OM columns h*20+t for every output row n = d (fragment layout)
    {
      const float* opr = opw + d*128;
      float acc[8] = {0,0,0,0,0,0,0,0};
      #pragma unroll
      for (int k4 = 0; k4 < 32; k4++) {
        float4 o4 = *(const float4*)&opr[k4*4];
        acc[k4 >> 2] += dot4(o4, *(const float4*)&vecB[k4*4]);
      }
      #pragma unroll
      for (int h = 0; h < 8; h++) OMw[om_off(d, h*20 + t)] = f2b(acc[h]);
    }
  } else {
    float suu = mean128(uh*uh, red);
    float sww = mean128(wh*wh, red);
    float suw = mean128(uh*wh, red);
    if (d == 0) {
      float* sc = (float*)(ws + WS_SCAL);
      sc[0] = suu; sc[1] = sww; sc[2] = suw;
    }
    vecA[d] = uh * g; vecB[d] = wh * g; vecC[d] = tln_b[d];
    __syncthreads();
    const float* wkr = ipw + (128 + d)*128;
    const float* wvr = ipw + (256 + d)*128;
    float ku = 0, kw = 0, kc = 0, vu = 0, vw = 0, vc = 0;
    for (int k4 = 0; k4 < 32; k4++) {
      float4 a4 = *(const float4*)&vecA[k4*4];
      float4 b4 = *(const float4*)&vecB[k4*4];
      float4 c4 = *(const float4*)&vecC[k4*4];
      float4 kv = *(const float4*)&wkr[k4*4];
      float4 vv = *(const float4*)&wvr[k4*4];
      ku += dot4(kv, a4); kw += dot4(kv, b4); kc += dot4(kv, c4);
      vu += dot4(vv, a4); vw += dot4(vv, b4); vc += dot4(vv, c4);
    }
    kc += ipb[128 + d]; vc += ipb[256 + d];
    kuA[d] = ku; kwA[d] = kw; kcA[d] = kc;
    float* qnw = (float*)(ws + WS_QN);
    qnw[0*128 + d] = qn[0][d]; qnw[1*128 + d] = qn[1][d]; qnw[2*128 + d] = qn[2][d];
    __syncthreads();
    // repurpose vecA/B/C to hold vu/vw/vc (all proj reads are done)
    vecA[d] = vu; vecB[d] = vw; vecC[d] = vc;
    __syncthreads();
    if (d < 24) {
      int w = d / 8, h = d % 8;
      float su = 0, sw = 0, sc2 = 0;
      #pragma unroll
      for (int dl = 0; dl < 16; dl++) {
        float q = qmat[w][h*16 + dl];
        su  += q * kuA[h*16 + dl];
        sw  += q * kwA[h*16 + dl];
        sc2 += q * kcA[h*16 + dl];
      }
      float* o = (float*)(ws + WS_SU);
      o[ 0 + w*8 + h] = 0.25f * su;
      o[24 + w*8 + h] = 0.25f * sw;
      o[48 + w*8 + h] = 0.25f * sc2;
    }
    // OM columns 160..191 (fragment layout)
    {
      const float* opr = opw + d*128;
      float au[8] = {0,0,0,0,0,0,0,0};
      float aw[8] = {0,0,0,0,0,0,0,0};
      float ac = 0;
      #pragma unroll
      for (int k4 = 0; k4 < 32; k4++) {
        float4 o4 = *(const float4*)&opr[k4*4];
        au[k4 >> 2] += dot4(o4, *(const float4*)&vecA[k4*4]);
        aw[k4 >> 2] += dot4(o4, *(const float4*)&vecB[k4*4]);
        ac          += dot4(o4, *(const float4*)&vecC[k4*4]);
      }
      #pragma unroll
      for (int h = 0; h < 8; h++) {
        OMw[om_off(d, 160 + h)] = f2b(au[h]);
        OMw[om_off(d, 168 + h)] = f2b(aw[h]);
      }
      OMw[om_off(d, 176)] = f2b(ac + opb[d]);
      #pragma unroll
      for (int i = 177; i < 192; i++) OMw[om_off(d, i)] = 0;
    }
  }
}

// ---------------------------------------------------------------------------
// Main fused kernel: 16 batch elements per WG (M = 48 rows), 256 threads.
// LDS 32256 B -> 5 WGs/CU under __launch_bounds__(256,5). 9 barriers.
#define GE 16
#define MR 48
#define SMEM_SZ 32256

__global__ __launch_bounds__(256, 5) void k_main(
    const float* __restrict__ tl, const float* __restrict__ tr,
    const float* __restrict__ f1b, const float* __restrict__ f2b_,
    const float* __restrict__ pag, const float* __restrict__ pab,
    const float* __restrict__ pfg, const float* __restrict__ pfb,
    const float* __restrict__ hw, const float* __restrict__ hb,
    const char* __restrict__ ws, float* __restrict__ out)
{
  __shared__ __align__(16) char smem[SMEM_SZ];
  // region A
  unsigned short* Z  = (unsigned short*)(smem);          // 48x200 (P0-P3)
  unsigned short* X  = (unsigned short*)(smem);          // 48x136 (aliases Z, post-b4)
  float* Pp2  = (float*)(smem + 13056);                  // [48][4] float2
  float* Op   = (float*)(smem + 14976);                  // [48][4] float2
  // region B
  float* xr   = (float*)(smem + 19200);                  // 16x20 (pre-scaled x*rv)
  float* yr   = (float*)(smem + 20480);
  float* rsA  = (float*)(smem + 21760);
  float* Sbl  = (float*)(smem + 23040);                  // 480
  float* SulA = (float*)(smem + 24960);                  // 72 (Su,Sw,Sc)
  float* QNl  = (float*)(smem + 25248);                  // 3x128
  float* pagl = (float*)(smem + 26784);                  // 128
  float* pabl = (float*)(smem + 27296);                  // 128
  float* Pp   = (float*)(smem + 27808);                  // [48][4] float2
  unsigned short* h1 = (unsigned short*)(smem + 19200);  // 48x136 (P5/P6)

  const unsigned short* OMf = (const unsigned short*)(ws + WS_OM);
  const unsigned short* W1f = (const unsigned short*)(ws + WS_FC1);
  const unsigned short* W2f = (const unsigned short*)(ws + WS_FC2);
  const float* QNw  = (const float*)(ws + WS_QN);
  const float* SBw  = (const float*)(ws + WS_SB);
  const float* SUw  = (const float*)(ws + WS_SU);
  const float* SCAL = (const float*)(ws + WS_SCAL);
  const float* SUB  = (const float*)(ws + WS_SUB);
  const float* SWB  = (const float*)(ws + WS_SWB);
  const float* SBB  = (const float*)(ws + WS_SBB);

  const int tid  = threadIdx.x;
  const int wg   = blockIdx.x;
  const int lane = tid & 63;
  const int wv   = tid >> 6;
  const int c    = lane & 15;     // MFMA column-in-tile / A-row index
  const int g    = lane >> 4;     // MFMA k-slice / output row-group
  const int nb   = wv * 32;       // N-slice base for this wave

  // ---- P0: stage tables, init Z constant tail, load coords + inline rs ----
  for (int i = tid; i < 480; i += 256) Sbl[i] = SBw[i];
  if (tid < 72) SulA[tid] = SUw[tid];
  for (int i = tid; i < 384; i += 256) QNl[i] = QNw[i];
  if (tid < 128) { pagl[tid] = pag[tid]; pabl[tid] = pab[tid]; }
  if (tid < 48) {
    unsigned short* Zr = Z + tid*200;
    Zr[176] = 0x3F80;                  // bf16 1.0
    #pragma unroll
    for (int i = 177; i < 192; i++) Zr[i] = 0;
  }
  if (tid < 160) {
    int half = tid / 80;               // 0 = left, 1 = right
    int i4   = tid % 80;
    const float* src = half ? tr : tl;
    float4 v = *(const float4*)(src + wg*(GE*20) + i4*4);
    int e  = i4 / 5;
    int j  = (i4 % 5) * 4;
    int t0 = half*10 + j/2;
    // inline rs for the loader's own two tokens (formulas = R8's P1,
    // tables read from GLOBAL -> no cross-thread dependency)
    float suu = SCAL[0], sww = SCAL[1], suw = SCAL[2];
    float var0 = suu*v.x*v.x + sww*v.y*v.y + 2.0f*suw*v.x*v.y
               + 2.0f*SUB[t0]*v.x + 2.0f*SWB[t0]*v.y + SBB[t0];
    float rv0 = rsqrtf(var0 + 1e-5f);
    float var1 = suu*v.z*v.z + sww*v.w*v.w + 2.0f*suw*v.z*v.w
               + 2.0f*SUB[t0+1]*v.z + 2.0f*SWB[t0+1]*v.w + SBB[t0+1];
    float rv1 = rsqrtf(var1 + 1e-5f);
    xr[e*20 + t0]      = v.x*rv0; yr[e*20 + t0]      = v.y*rv0; rsA[e*20 + t0]      = rv0;
    xr[e*20 + t0 + 1]  = v.z*rv1; yr[e*20 + t0 + 1]  = v.w*rv1; rsA[e*20 + t0 + 1]  = rv1;
  }
  __syncthreads();                                        // b1

  // ---- P2: scores + softmax + P,Q -> Z rows (bf16), ALL 256 threads ----
  // waves 0-1: w = 0 then 1 for (e,h); waves 2-3: w = 2 only.  (= R8)
  {
    const int e = (tid & 127) >> 3;
    const int h = tid & 7;
    const int whalf = tid >> 7;
    float xa[20], ya[20], ra[20];
    #pragma unroll
    for (int tb = 0; tb < 5; tb++) {
      float4 xv = *(const float4*)&xr[e*20 + tb*4];
      float4 yv = *(const float4*)&yr[e*20 + tb*4];
      float4 rv = *(const float4*)&rsA[e*20 + tb*4];
      xa[tb*4+0]=xv.x; xa[tb*4+1]=xv.y; xa[tb*4+2]=xv.z; xa[tb*4+3]=xv.w;
      ya[tb*4+0]=yv.x; ya[tb*4+1]=yv.y; ya[tb*4+2]=yv.z; ya[tb*4+3]=yv.w;
      ra[tb*4+0]=rv.x; ra[tb*4+1]=rv.y; ra[tb*4+2]=rv.z; ra[tb*4+3]=rv.w;
    }
    const int nu = whalf ? 1 : 2;
    for (int it = 0; it < nu; it++) {
      const int w = whalf ? 2 : it;
      float suv = SulA[w*8 + h], swv = SulA[24 + w*8 + h], scv = SulA[48 + w*8 + h];
      const float* sb = &Sbl[(w*8 + h)*20];
      float s[20];
      #pragma unroll
      for (int tb = 0; tb < 5; tb++) {
        float4 s4 = *(const float4*)&sb[tb*4];
        s[tb*4+0] = fmaf(xa[tb*4+0],suv, fmaf(ya[tb*4+0],swv, fmaf(ra[tb*4+0],s4.x, scv)));
        s[tb*4+1] = fmaf(xa[tb*4+1],suv, fmaf(ya[tb*4+1],swv, fmaf(ra[tb*4+1],s4.y, scv)));
        s[tb*4+2] = fmaf(xa[tb*4+2],suv, fmaf(ya[tb*4+2],swv, fmaf(ra[tb*4+2],s4.z, scv)));
        s[tb*4+3] = fmaf(xa[tb*4+3],suv, fmaf(ya[tb*4+3],swv, fmaf(ra[tb*4+3],s4.w, scv)));
      }
      float m = s[0];
      #pragma unroll
      for (int t2 = 1; t2 < 20; t2++) m = fmaxf(m, s[t2]);
      float sum = 0;
      #pragma unroll
      for (int t2 = 0; t2 < 20; t2++) { float p = __expf(s[t2] - m); s[t2] = p; sum += p; }
      float inv = 1.0f / sum;
      float P = 0, Q = 0;
      #pragma unroll
      for (int t2 = 0; t2 < 20; t2++) { P = fmaf(s[t2], xa[t2], P); Q = fmaf(s[t2], ya[t2], Q); }
      P *= inv; Q *= inv;
      unsigned short* Zr = Z + (e*3 + w)*200;
      #pragma unroll
      for (int t2 = 0; t2 < 10; t2++) {
        unsigned int lo = f2b(s[2*t2]   * ra[2*t2]   * inv);
        unsigned int hi = f2b(s[2*t2+1] * ra[2*t2+1] * inv);
        *(unsigned int*)&Zr[h*20 + 2*t2] = lo | (hi << 16);
      }
      Zr[160 + h] = f2b(P);
      Zr[168 + h] = f2b(Q);
    }
  }
  // Prefetch OM fragments (no Z dependency -> in flight across b3)
  bf16x8 BfOM[2][6];
  #pragma unroll
  for (int nt = 0; nt < 2; nt++)
    #pragma unroll
    for (int kt = 0; kt < 6; kt++)
      BfOM[nt][kt] = *(const bf16x8*)(OMf + ((wv*2 + nt)*6 + kt)*512 + lane*8);
  __syncthreads();                                        // b3

  // ---- P3: GEMM1 attn_out = Z(48x192) @ OM^T, fused LN -> X bf16 ----
  {
    f32x4 acc[3][2];
    #pragma unroll
    for (int mt = 0; mt < 3; mt++)
      #pragma unroll
      for (int nt = 0; nt < 2; nt++) acc[mt][nt] = (f32x4){0.f,0.f,0.f,0.f};
    #pragma unroll
    for (int kt = 0; kt < 6; kt++) {
      bf16x8 Af[3];
      #pragma unroll
      for (int mt = 0; mt < 3; mt++)
        Af[mt] = *(const bf16x8*)(Z + (mt*16 + c)*200 + kt*32 + g*8);
      #pragma unroll
      for (int mt = 0; mt < 3; mt++)
        #pragma unroll
        for (int nt = 0; nt < 2; nt++)
          acc[mt][nt] = mfma16(Af[mt], BfOM[nt][kt], acc[mt][nt]);
    }
    // fragment-LN: add queries_n, column-group reduce for mean/var
    float p1[3][4], p2[3][4];
    #pragma unroll
    for (int mt = 0; mt < 3; mt++)
      #pragma unroll
      for (int j = 0; j < 4; j++) {
        int row = mt*16 + g*4 + j;
        int w = row % 3;
        float v0 = acc[mt][0][j] + QNl[w*128 + nb + c];
        float v1 = acc[mt][1][j] + QNl[w*128 + nb + 16 + c];
        acc[mt][0][j] = v0; acc[mt][1][j] = v1;
        p1[mt][j] = v0 + v1;
        p2[mt][j] = v0*v0 + v1*v1;
      }
    #pragma unroll
    for (int mt = 0; mt < 3; mt++)
      #pragma unroll
      for (int j = 0; j < 4; j++) {
        #pragma unroll
        for (int mk = 1; mk <= 8; mk <<= 1) {
          p1[mt][j] += __shfl_xor(p1[mt][j], mk, 64);
          p2[mt][j] += __shfl_xor(p2[mt][j], mk, 64);
        }
      }
    if (c < 4) {
      #pragma unroll
      for (int mt = 0; mt < 3; mt++) {
        float a = (c==0)?p1[mt][0]:(c==1)?p1[mt][1]:(c==2)?p1[mt][2]:p1[mt][3];
        float b = (c==0)?p2[mt][0]:(c==1)?p2[mt][1]:(c==2)?p2[mt][2]:p2[mt][3];
        int row = mt*16 + g*4 + c;
        *(float2*)&Pp[row*8 + wv*2] = make_float2(a, b);
      }
    }
    __syncthreads();                                      // b4: Pp ready, Z dead
    // X = LN'd x; m/sc recomputed per thread from Pp (broadcast reads)
    {
      float pg0 = pagl[nb + c],      pb0 = pabl[nb + c];
      float pg1 = pagl[nb + 16 + c], pb1 = pabl[nb + 16 + c];
      #pragma unroll
      for (int mt = 0; mt < 3; mt++)
        #pragma unroll
        for (int j = 0; j < 4; j++) {
          int row = mt*16 + g*4 + j;
          float4 a = *(const float4*)&Pp[row*8];
          float4 b = *(const float4*)&Pp[row*8 + 4];
          float s1 = a.x + a.z + b.x + b.z;
          float s2 = a.y + a.w + b.y + b.w;
          float m  = s1 * (1.0f/128.0f);
          float sc = rsqrtf(s2 * (1.0f/128.0f) - m*m + 1e-5f);
          X[row*136 + nb + c]      = f2b((acc[mt][0][j] - m)*sc*pg0 + pb0);
          X[row*136 + nb + 16 + c] = f2b((acc[mt][1][j] - m)*sc*pg1 + pb1);
        }
    }
  }
  // Prefetch W1 half 0 (no dependency -> in flight across b5)
  bf16x8 BfW1[2][4];
  #pragma unroll
  for (int nt = 0; nt < 2; nt++)
    #pragma unroll
    for (int kt = 0; kt < 4; kt++)
      BfW1[nt][kt] = *(const bf16x8*)(W1f + ((wv*2 + nt)*4 + kt)*512 + lane*8);
  __syncthreads();                                        // b5: X ready

  // ---- P5/P6: FFN in two K=128 halves sharing h1 (48x136 bf16) ----
  f32x4 acc2[3][2];
  #pragma unroll
  for (int mt = 0; mt < 3; mt++)
    #pragma unroll
    for (int nt = 0; nt < 2; nt++) acc2[mt][nt] = (f32x4){0.f,0.f,0.f,0.f};

  #pragma unroll
  for (int h = 0; h < 2; h++) {
    // P5: fc1 half -> relu -> h1 (BfW1 prefetched)
    {
      f32x4 acc[3][2];
      #pragma unroll
      for (int mt = 0; mt < 3; mt++)
        #pragma unroll
        for (int nt = 0; nt < 2; nt++) acc[mt][nt] = (f32x4){0.f,0.f,0.f,0.f};
      #pragma unroll
      for (int kt = 0; kt < 4; kt++) {
        bf16x8 Af[3];
        #pragma unroll
        for (int mt = 0; mt < 3; mt++)
          Af[mt] = *(const bf16x8*)(X + (mt*16 + c)*136 + kt*32 + g*8);
        #pragma unroll
        for (int mt = 0; mt < 3; mt++)
          #pragma unroll
          for (int nt = 0; nt < 2; nt++)
            acc[mt][nt] = mfma16(Af[mt], BfW1[nt][kt], acc[mt][nt]);
      }
      float bb0 = f1b[h*128 + nb + c];
      float bb1 = f1b[h*128 + nb + 16 + c];
      #pragma unroll
      for (int mt = 0; mt < 3; mt++)
        #pragma unroll
        for (int j = 0; j < 4; j++) {
          int row = mt*16 + g*4 + j;
          h1[row*136 + nb + c]      = f2b(fmaxf(acc[mt][0][j] + bb0, 0.0f));
          h1[row*136 + nb + 16 + c] = f2b(fmaxf(acc[mt][1][j] + bb1, 0.0f));
        }
    }
    // Prefetch W2 for this half (in flight across the h1-ready barrier)
    bf16x8 BfW2[2][4];
    #pragma unroll
    for (int nt = 0; nt < 2; nt++)
      #pragma unroll
      for (int kt = 0; kt < 4; kt++)
        BfW2[nt][kt] = *(const bf16x8*)(W2f + ((wv*2 + nt)*8 + h*4 + kt)*512 + lane*8);
    __syncthreads();                                      // b6 / b8: h1 ready
    // P6: fc2 partial over this K-half, accumulate into acc2
    #pragma unroll
    for (int kt = 0; kt < 4; kt++) {
      bf16x8 Af[3];
      #pragma unroll
      for (int mt = 0; mt < 3; mt++)
        Af[mt] = *(const bf16x8*)(h1 + (mt*16 + c)*136 + kt*32 + g*8);
      #pragma unroll
      for (int mt = 0; mt < 3; mt++)
        #pragma unroll
        for (int nt = 0; nt < 2; nt++)
          acc2[mt][nt] = mfma16(Af[mt], BfW2[nt][kt], acc2[mt][nt]);
    }
    if (h == 0) {
      // Prefetch W1 half 1 (in flight across the h1-rewrite barrier)
      #pragma unroll
      for (int nt = 0; nt < 2; nt++)
        #pragma unroll
        for (int kt = 0; kt < 4; kt++)
          BfW1[nt][kt] = *(const bf16x8*)(W1f + ((8 + wv*2 + nt)*4 + kt)*512 + lane*8);
      __syncthreads();                                    // b7 (h1 rewrite guard)
    }
  }

  // ---- P6b epilogue: h2+bias+residual -> fragment-LN -> head -> out ----
  {
    float bb0 = f2b_[nb + c];
    float bb1 = f2b_[nb + 16 + c];
    float p1[3][4], p2[3][4];
    #pragma unroll
    for (int mt = 0; mt < 3; mt++)
      #pragma unroll
      for (int j = 0; j < 4; j++) {
        int row = mt*16 + g*4 + j;
        float v0 = acc2[mt][0][j] + bb0 + b2f(X[row*136 + nb + c]);
        float v1 = acc2[mt][1][j] + bb1 + b2f(X[row*136 + nb + 16 + c]);
        acc2[mt][0][j] = v0; acc2[mt][1][j] = v1;
        p1[mt][j] = v0 + v1;
        p2[mt][j] = v0*v0 + v1*v1;
      }
    #pragma unroll
    for (int mt = 0; mt < 3; mt++)
      #pragma unroll
      for (int j = 0; j < 4; j++) {
        #pragma unroll
        for (int mk = 1; mk <= 8; mk <<= 1) {
          p1[mt][j] += __shfl_xor(p1[mt][j], mk, 64);
          p2[mt][j] += __shfl_xor(p2[mt][j], mk, 64);
        }
      }
    if (c < 4) {
      #pragma unroll
      for (int mt = 0; mt < 3; mt++) {
        float a = (c==0)?p1[mt][0]:(c==1)?p1[mt][1]:(c==2)?p1[mt][2]:p1[mt][3];
        float b = (c==0)?p2[mt][0]:(c==1)?p2[mt][1]:(c==2)?p2[mt][2]:p2[mt][3];
        int row = mt*16 + g*4 + c;
        *(float2*)&Pp2[row*8 + wv*2] = make_float2(a, b);
      }
    }
    __syncthreads();                                      // b9: Pp2 ready
    // m/sc per thread from Pp2 (broadcast); head partials; cross-wave Op
    {
      float fg0 = pfg[nb + c],        fb0 = pfb[nb + c];
      float fg1 = pfg[nb + 16 + c],   fb1 = pfb[nb + 16 + c];
      float hw00 = hw[nb + c],        hw01 = hw[nb + 16 + c];
      float hw10 = hw[128 + nb + c],  hw11 = hw[128 + nb + 16 + c];
      float o0[3][4], o1[3][4];
      #pragma unroll
      for (int mt = 0; mt < 3; mt++)
        #pragma unroll
        for (int j = 0; j < 4; j++) {
          int row = mt*16 + g*4 + j;
          float4 a = *(const float4*)&Pp2[row*8];
          float4 b = *(const float4*)&Pp2[row*8 + 4];
          float s1 = a.x + a.z + b.x + b.z;
          float s2 = a.y + a.w + b.y + b.w;
          float m  = s1 * (1.0f/128.0f);
          float sc = rsqrtf(s2 * (1.0f/128.0f) - m*m + 1e-5f);
          float x0 = (acc2[mt][0][j] - m)*sc*fg0 + fb0;
          float x1 = (acc2[mt][1][j] - m)*sc*fg1 + fb1;
          o0[mt][j] = x0*hw00 + x1*hw01;
          o1[mt][j] = x0*hw10 + x1*hw11;
        }
      #pragma unroll
      for (int mt = 0; mt < 3; mt++)
        #pragma unroll
        for (int j = 0; j < 4; j++) {
          #pragma unroll
          for (int mk = 1; mk <= 8; mk <<= 1) {
            o0[mt][j] += __shfl_xor(o0[mt][j], mk, 64);
            o1[mt][j] += __shfl_xor(o1[mt][j], mk, 64);
          }
        }
      if (c < 4) {
        #pragma unroll
        for (int mt = 0; mt < 3; mt++) {
          float a = (c==0)?o0[mt][0]:(c==1)?o0[mt][1]:(c==2)?o0[mt][2]:o0[mt][3];
          float b = (c==0)?o1[mt][0]:(c==1)?o1[mt][1]:(c==2)?o1[mt][2]:o1[mt][3];
          int row = mt*16 + g*4 + c;
          *(float2*)&Op[row*8 + wv*2] = make_float2(a, b);
        }
      }
    }
    __syncthreads();                                      // b10: Op ready
    if (tid < 48) {
      float4 a = *(const float4*)&Op[tid*8];
      float4 b = *(const float4*)&Op[tid*8 + 4];
      out[(wg*48 + tid)*2]     = a.x + a.z + b.x + b.z + hb[0];
      out[(wg*48 + tid)*2 + 1] = a.y + a.w + b.y + b.w + hb[1];
    }
  }
}

// ---------------------------------------------------------------------------
extern "C" void kernel_launch(void* const* d_in, const int* in_sizes, int n_in,
                              void* d_out, int out_size, void* d_ws, size_t ws_size,
                              hipStream_t stream) {
  const float* tl       = (const float*)d_in[0];
  const float* tr       = (const float*)d_in[1];
  const float* coord_w  = (const float*)d_in[2];
  const float* coord_b  = (const float*)d_in[3];
  const float* pos_emb  = (const float*)d_in[4];
  const float* side_emb = (const float*)d_in[5];
  const float* query_emb= (const float*)d_in[6];
  const float* tln_g    = (const float*)d_in[7];
  const float* tln_b    = (const float*)d_in[8];
  const float* qln_g    = (const float*)d_in[9];
  const float* qln_b    = (const float*)d_in[10];
  const float* ipw      = (const float*)d_in[11];
  const float* ipb      = (const float*)d_in[12];
  const float* opw      = (const float*)d_in[13];
  const float* opb      = (const float*)d_in[14];
  const float* f1w      = (const float*)d_in[15];
  const float* f1b      = (const float*)d_in[16];
  const float* f2w      = (const float*)d_in[17];
  const float* f2b2     = (const float*)d_in[18];
  const float* pag      = (const float*)d_in[19];
  const float* pab      = (const float*)d_in[20];
  const float* pfg      = (const float*)d_in[21];
  const float* pfb      = (const float*)d_in[22];
  const float* hw       = (const float*)d_in[23];
  const float* hb       = (const float*)d_in[24];
  char* ws = (char*)d_ws;

  k_prep<<<53, 128, 0, stream>>>(coord_w, coord_b, pos_emb, side_emb, query_emb,
                                 tln_g, tln_b, qln_g, qln_b, ipw, ipb,
                                 opw, opb, f1w, f2w, ws);
  k_main<<<32768 / GE, 256, 0, stream>>>(tl, tr, f1b, f2b2, pag, pab, pfg, pfb,
                                         hw, hb, ws, (float*)d_out);
}

// Round 14
// 172.290 us; speedup vs baseline: 1.0598x; 1.0598x over previous
//
#include <hip/hip_runtime.h>
#include <hip/hip_bf16.h>

// ---------------------------------------------------------------------------
// TransformerPlanner: algebra-collapsed fused implementation.
//
// R14 = R12 verbatim (best-measured passing kernel: k_main 64.0us, total
// 173.7us; 215.9 -> 173.7 over the session, -20%).
// R13's (256,5) experiment proved the launch bound never capped residency
// (Occ ~35% both ways) and only squeezed VGPR 60->48 causing a spill storm
// (WRITE 59MB). Plateau analysis: k_main = 63.8-65.2us across ALL correct
// structural variants (barriers 12/10/9, softmax splits, spills on/off,
// prefetch, fragment-ordered B); ~109us of total is harness-fixed.
// This is the practical floor for this design.
// ---------------------------------------------------------------------------

typedef __bf16 bf16x8 __attribute__((ext_vector_type(8)));
typedef float  f32x4  __attribute__((ext_vector_type(4)));
static_assert(sizeof(bf16x8) == 16, "bf16x8 must be 16B");

__device__ __forceinline__ unsigned short f2b(float x) {
  __bf16 h = (__bf16)x;
  return __builtin_bit_cast(unsigned short, h);
}
__device__ __forceinline__ float b2f(unsigned short u) {
  return (float)__builtin_bit_cast(__bf16, u);
}
__device__ __forceinline__ float dot4(float4 a, float4 b) {
  return a.x*b.x + a.y*b.y + a.z*b.z + a.w*b.w;
}
__device__ __forceinline__ f32x4 mfma16(bf16x8 a, bf16x8 b, f32x4 c) {
  return __builtin_amdgcn_mfma_f32_16x16x32_bf16(a, b, c, 0, 0, 0);
}

// Fragment-order offsets (ushort index) for B matrices:
// lane l of a (ntile,ktile) block holds n = ntile*16 + (l&15),
// k = ktile*32 + (l>>4)*8 .. +8. Block = 64 lanes x 8 ushort = 512.
__device__ __forceinline__ int om_off(int n, int k) {   // 128x192, 6 ktiles
  return (((n >> 4)*6 + (k >> 5))*64 + ((k >> 3) & 3)*16 + (n & 15))*8 + (k & 7);
}
__device__ __forceinline__ int w1_off(int n, int k) {   // 256x128, 4 ktiles
  return (((n >> 4)*4 + (k >> 5))*64 + ((k >> 3) & 3)*16 + (n & 15))*8 + (k & 7);
}
__device__ __forceinline__ int w2_off(int n, int k) {   // 128x256, 8 ktiles
  return (((n >> 4)*8 + (k >> 5))*64 + ((k >> 3) & 3)*16 + (n & 15))*8 + (k & 7);
}

// ---- workspace layout (byte offsets into d_ws) ----
#define WS_OM    0          // ushort[24576]  OM fragments (8 ntile x 6 ktile)
#define WS_FC1   49152      // ushort[32768]  fc1 fragments (16 x 4)
#define WS_FC2   114688     // ushort[32768]  fc2 fragments (8 x 8)
#define WS_QN    192000     // float[3*128]  LN'd queries
#define WS_SB    193536     // float[480]    Sb[w][h][t]
#define WS_SU    195456     // float[72]     Su[24],Sw[24],Sc[24]
#define WS_SCAL  195744     // float[3]      Suu,Sww,Suw
#define WS_SUB   195756     // float[20]
#define WS_SWB   195836     // float[20]
#define WS_SBB   195916     // float[20]

// ---------------------------------------------------------------------------
__device__ float mean128(float v, volatile float* red) {
  #pragma unroll
  for (int o = 32; o; o >>= 1) v += __shfl_down(v, o, 64);
  __syncthreads();
  if ((threadIdx.x & 63) == 0) red[threadIdx.x >> 6] = v;
  __syncthreads();
  return (red[0] + red[1]) * (1.0f / 128.0f);
}

// Merged prep kernel: 53 blocks x 128 threads. (proven R7/R8/R12)
__global__ void k_prep(
    const float* __restrict__ coord_w, const float* __restrict__ coord_b,
    const float* __restrict__ pos_emb, const float* __restrict__ side_emb,
    const float* __restrict__ query_emb,
    const float* __restrict__ tln_g, const float* __restrict__ tln_b,
    const float* __restrict__ qln_g, const float* __restrict__ qln_b,
    const float* __restrict__ ipw, const float* __restrict__ ipb,
    const float* __restrict__ opw, const float* __restrict__ opb,
    const float* __restrict__ f1w, const float* __restrict__ f2w,
    char* __restrict__ ws)
{
  const int b = blockIdx.x, tid = threadIdx.x;   // 128 threads
  if (b >= 21) {
    if (b < 37) {
      unsigned short* dst = (unsigned short*)(ws + WS_FC1);
      int i0 = (b - 21)*2048;
      #pragma unroll
      for (int j = 0; j < 16; j++) {
        int i = i0 + j*128 + tid;
        dst[w1_off(i >> 7, i & 127)] = f2b(f1w[i]);
      }
    } else {
      unsigned short* dst = (unsigned short*)(ws + WS_FC2);
      int i0 = (b - 37)*2048;
      #pragma unroll
      for (int j = 0; j < 16; j++) {
        int i = i0 + j*128 + tid;
        dst[w2_off(i >> 8, i & 255)] = f2b(f2w[i]);
      }
    }
    return;
  }

  __shared__ float red[2];
  __shared__ float qn[3][128];
  __shared__ float qmat[3][128];
  __shared__ float vecA[128];
  __shared__ float vecB[128];
  __shared__ float vecC[128];
  __shared__ float kuA[128];
  __shared__ float kwA[128];
  __shared__ float kcA[128];
  const int d = tid;
  const int t = b;                // 0..19 = token blocks, 20 = misc
  unsigned short* OMw = (unsigned short*)(ws + WS_OM);

  float u  = coord_w[d*2+0];
  float w2 = coord_w[d*2+1];
  float g  = tln_g[d];
  float mu = mean128(u,  red);
  float mw = mean128(w2, red);
  float uh = u - mu, wh = w2 - mw;

  // LN(query_emb)
  #pragma unroll
  for (int w = 0; w < 3; w++) {
    float qe = query_emb[w*128 + d];
    float m  = mean128(qe, red);
    float m2 = mean128(qe*qe, red);
    float var = m2 - m*m;
    qn[w][d] = (qe - m) * rsqrtf(var + 1e-5f) * qln_g[d] + qln_b[d];
  }
  __syncthreads();
  // q = qn @ wq^T + bq
  {
    const float* wqr = ipw + d*128;
    float a0 = 0, a1 = 0, a2 = 0;
    for (int k4 = 0; k4 < 32; k4++) {
      float4 wv4 = *(const float4*)&wqr[k4*4];
      a0 += dot4(wv4, *(const float4*)&qn[0][k4*4]);
      a1 += dot4(wv4, *(const float4*)&qn[1][k4*4]);
      a2 += dot4(wv4, *(const float4*)&qn[2][k4*4]);
    }
    float bq = ipb[d];
    qmat[0][d] = a0 + bq; qmat[1][d] = a1 + bq; qmat[2][d] = a2 + bq;
  }
  __syncthreads();

  if (t < 20) {
    float base = coord_b[d] + pos_emb[(t % 10)*128 + d] + side_emb[(t < 10 ? 0 : 1)*128 + d];
    float mb = mean128(base, red);
    float bh = base - mb;
    float sub = mean128(uh*bh, red);
    float swb = mean128(wh*bh, red);
    float sbb = mean128(bh*bh, red);
    if (d == 0) {
      ((float*)(ws + WS_SUB))[t] = sub;
      ((float*)(ws + WS_SWB))[t] = swb;
      ((float*)(ws + WS_SBB))[t] = sbb;
    }
    vecA[d] = bh * g;
    __syncthreads();
    const float* wkr = ipw + (128 + d)*128;
    const float* wvr = ipw + (256 + d)*128;
    float kb = 0, vb = 0;
    for (int k4 = 0; k4 < 32; k4++) {
      float4 a4 = *(const float4*)&vecA[k4*4];
      kb += dot4(*(const float4*)&wkr[k4*4], a4);
      vb += dot4(*(const float4*)&wvr[k4*4], a4);
    }
    kuA[d] = kb;
    vecB[d] = vb;
    __syncthreads();
    if (d < 24) {
      int w = d / 8, h = d % 8;
      float s = 0;
      #pragma unroll
      for (int dl = 0; dl < 16; dl++) s += qmat[w][h*16 + dl] * kuA[h*16 + dl];
      ((float*)(ws + WS_SB))[(w*8 + h)*20 + t] = 0.25f * s;
    }
    // OM columns h*20+t for every output row n = d (fragment layout)
    {
      const float* opr = opw + d*128;
      float acc[8] = {0,0,0,0,0,0,0,0};
      #pragma unroll
      for (int k4 = 0; k4 < 32; k4++) {
        float4 o4 = *(const float4*)&opr[k4*4];
        acc[k4 >> 2] += dot4(o4, *(const float4*)&vecB[k4*4]);
      }
      #pragma unroll
      for (int h = 0; h < 8; h++) OMw[om_off(d, h*20 + t)] = f2b(acc[h]);
    }
  } else {
    float suu = mean128(uh*uh, red);
    float sww = mean128(wh*wh, red);
    float suw = mean128(uh*wh, red);
    if (d == 0) {
      float* sc = (float*)(ws + WS_SCAL);
      sc[0] = suu; sc[1] = sww; sc[2] = suw;
    }
    vecA[d] = uh * g; vecB[d] = wh * g; vecC[d] = tln_b[d];
    __syncthreads();
    const float* wkr = ipw + (128 + d)*128;
    const float* wvr = ipw + (256 + d)*128;
    float ku = 0, kw = 0, kc = 0, vu = 0, vw = 0, vc = 0;
    for (int k4 = 0; k4 < 32; k4++) {
      float4 a4 = *(const float4*)&vecA[k4*4];
      float4 b4 = *(const float4*)&vecB[k4*4];
      float4 c4 = *(const float4*)&vecC[k4*4];
      float4 kv = *(const float4*)&wkr[k4*4];
      float4 vv = *(const float4*)&wvr[k4*4];
      ku += dot4(kv, a4); kw += dot4(kv, b4); kc += dot4(kv, c4);
      vu += dot4(vv, a4); vw += dot4(vv, b4); vc += dot4(vv, c4);
    }
    kc += ipb[128 + d]; vc += ipb[256 + d];
    kuA[d] = ku; kwA[d] = kw; kcA[d] = kc;
    float* qnw = (float*)(ws + WS_QN);
    qnw[0*128 + d] = qn[0][d]; qnw[1*128 + d] = qn[1][d]; qnw[2*128 + d] = qn[2][d];
    __syncthreads();
    // repurpose vecA/B/C to hold vu/vw/vc (all proj reads are done)
    vecA[d] = vu; vecB[d] = vw; vecC[d] = vc;
    __syncthreads();
    if (d < 24) {
      int w = d / 8, h = d % 8;
      float su = 0, sw = 0, sc2 = 0;
      #pragma unroll
      for (int dl = 0; dl < 16; dl++) {
        float q = qmat[w][h*16 + dl];
        su  += q * kuA[h*16 + dl];
        sw  += q * kwA[h*16 + dl];
        sc2 += q * kcA[h*16 + dl];
      }
      float* o = (float*)(ws + WS_SU);
      o[ 0 + w*8 + h] = 0.25f * su;
      o[24 + w*8 + h] = 0.25f * sw;
      o[48 + w*8 + h] = 0.25f * sc2;
    }
    // OM columns 160..191 (fragment layout)
    {
      const float* opr = opw + d*128;
      float au[8] = {0,0,0,0,0,0,0,0};
      float aw[8] = {0,0,0,0,0,0,0,0};
      float ac = 0;
      #pragma unroll
      for (int k4 = 0; k4 < 32; k4++) {
        float4 o4 = *(const float4*)&opr[k4*4];
        au[k4 >> 2] += dot4(o4, *(const float4*)&vecA[k4*4]);
        aw[k4 >> 2] += dot4(o4, *(const float4*)&vecB[k4*4]);
        ac          += dot4(o4, *(const float4*)&vecC[k4*4]);
      }
      #pragma unroll
      for (int h = 0; h < 8; h++) {
        OMw[om_off(d, 160 + h)] = f2b(au[h]);
        OMw[om_off(d, 168 + h)] = f2b(aw[h]);
      }
      OMw[om_off(d, 176)] = f2b(ac + opb[d]);
      #pragma unroll
      for (int i = 177; i < 192; i++) OMw[om_off(d, i)] = 0;
    }
  }
}

// ---------------------------------------------------------------------------
// Main fused kernel: 16 batch elements per WG (M = 48 rows), 256 threads.
// LDS 32256 B; __launch_bounds__(256,4). 9 barriers.
#define GE 16
#define MR 48
#define SMEM_SZ 32256

__global__ __launch_bounds__(256, 4) void k_main(
    const float* __restrict__ tl, const float* __restrict__ tr,
    const float* __restrict__ f1b, const float* __restrict__ f2b_,
    const float* __restrict__ pag, const float* __restrict__ pab,
    const float* __restrict__ pfg, const float* __restrict__ pfb,
    const float* __restrict__ hw, const float* __restrict__ hb,
    const char* __restrict__ ws, float* __restrict__ out)
{
  __shared__ __align__(16) char smem[SMEM_SZ];
  // region A
  unsigned short* Z  = (unsigned short*)(smem);          // 48x200 (P0-P3)
  unsigned short* X  = (unsigned short*)(smem);          // 48x136 (aliases Z, post-b4)
  float* Pp2  = (float*)(smem + 13056);                  // [48][4] float2
  float* Op   = (float*)(smem + 14976);                  // [48][4] float2
  // region B
  float* xr   = (float*)(smem + 19200);                  // 16x20 (pre-scaled x*rv)
  float* yr   = (float*)(smem + 20480);
  float* rsA  = (float*)(smem + 21760);
  float* Sbl  = (float*)(smem + 23040);                  // 480
  float* SulA = (float*)(smem + 24960);                  // 72 (Su,Sw,Sc)
  float* QNl  = (float*)(smem + 25248);                  // 3x128
  float* pagl = (float*)(smem + 26784);                  // 128
  float* pabl = (float*)(smem + 27296);                  // 128
  float* Pp   = (float*)(smem + 27808);                  // [48][4] float2
  unsigned short* h1 = (unsigned short*)(smem + 19200);  // 48x136 (P5/P6)

  const unsigned short* OMf = (const unsigned short*)(ws + WS_OM);
  const unsigned short* W1f = (const unsigned short*)(ws + WS_FC1);
  const unsigned short* W2f = (const unsigned short*)(ws + WS_FC2);
  const float* QNw  = (const float*)(ws + WS_QN);
  const float* SBw  = (const float*)(ws + WS_SB);
  const float* SUw  = (const float*)(ws + WS_SU);
  const float* SCAL = (const float*)(ws + WS_SCAL);
  const float* SUB  = (const float*)(ws + WS_SUB);
  const float* SWB  = (const float*)(ws + WS_SWB);
  const float* SBB  = (const float*)(ws + WS_SBB);

  const int tid  = threadIdx.x;
  const int wg   = blockIdx.x;
  const int lane = tid & 63;
  const int wv   = tid >> 6;
  const int c    = lane & 15;     // MFMA column-in-tile / A-row index
  const int g    = lane >> 4;     // MFMA k-slice / output row-group
  const int nb   = wv * 32;       // N-slice base for this wave

  // ---- P0: stage tables, init Z constant tail, load coords + inline rs ----
  for (int i = tid; i < 480; i += 256) Sbl[i] = SBw[i];
  if (tid < 72) SulA[tid] = SUw[tid];
  for (int i = tid; i < 384; i += 256) QNl[i] = QNw[i];
  if (tid < 128) { pagl[tid] = pag[tid]; pabl[tid] = pab[tid]; }
  if (tid < 48) {
    unsigned short* Zr = Z + tid*200;
    Zr[176] = 0x3F80;                  // bf16 1.0
    #pragma unroll
    for (int i = 177; i < 192; i++) Zr[i] = 0;
  }
  if (tid < 160) {
    int half = tid / 80;               // 0 = left, 1 = right
    int i4   = tid % 80;
    const float* src = half ? tr : tl;
    float4 v = *(const float4*)(src + wg*(GE*20) + i4*4);
    int e  = i4 / 5;
    int j  = (i4 % 5) * 4;
    int t0 = half*10 + j/2;
    // inline rs for the loader's own two tokens (formulas = R8's P1,
    // tables read from GLOBAL -> no cross-thread dependency)
    float suu = SCAL[0], sww = SCAL[1], suw = SCAL[2];
    float var0 = suu*v.x*v.x + sww*v.y*v.y + 2.0f*suw*v.x*v.y
               + 2.0f*SUB[t0]*v.x + 2.0f*SWB[t0]*v.y + SBB[t0];
    float rv0 = rsqrtf(var0 + 1e-5f);
    float var1 = suu*v.z*v.z + sww*v.w*v.w + 2.0f*suw*v.z*v.w
               + 2.0f*SUB[t0+1]*v.z + 2.0f*SWB[t0+1]*v.w + SBB[t0+1];
    float rv1 = rsqrtf(var1 + 1e-5f);
    xr[e*20 + t0]      = v.x*rv0; yr[e*20 + t0]      = v.y*rv0; rsA[e*20 + t0]      = rv0;
    xr[e*20 + t0 + 1]  = v.z*rv1; yr[e*20 + t0 + 1]  = v.w*rv1; rsA[e*20 + t0 + 1]  = rv1;
  }
  __syncthreads();                                        // b1

  // ---- P2: scores + softmax + P,Q -> Z rows (bf16), ALL 256 threads ----
  // waves 0-1: w = 0 then 1 for (e,h); waves 2-3: w = 2 only.
  {
    const int e = (tid & 127) >> 3;
    const int h = tid & 7;
    const int whalf = tid >> 7;
    float xa[20], ya[20], ra[20];
    #pragma unroll
    for (int tb = 0; tb < 5; tb++) {
      float4 xv = *(const float4*)&xr[e*20 + tb*4];
      float4 yv = *(const float4*)&yr[e*20 + tb*4];
      float4 rv = *(const float4*)&rsA[e*20 + tb*4];
      xa[tb*4+0]=xv.x; xa[tb*4+1]=xv.y; xa[tb*4+2]=xv.z; xa[tb*4+3]=xv.w;
      ya[tb*4+0]=yv.x; ya[tb*4+1]=yv.y; ya[tb*4+2]=yv.z; ya[tb*4+3]=yv.w;
      ra[tb*4+0]=rv.x; ra[tb*4+1]=rv.y; ra[tb*4+2]=rv.z; ra[tb*4+3]=rv.w;
    }
    const int nu = whalf ? 1 : 2;
    for (int it = 0; it < nu; it++) {
      const int w = whalf ? 2 : it;
      float suv = SulA[w*8 + h], swv = SulA[24 + w*8 + h], scv = SulA[48 + w*8 + h];
      const float* sb = &Sbl[(w*8 + h)*20];
      float s[20];
      #pragma unroll
      for (int tb = 0; tb < 5; tb++) {
        float4 s4 = *(const float4*)&sb[tb*4];
        s[tb*4+0] = fmaf(xa[tb*4+0],suv, fmaf(ya[tb*4+0],swv, fmaf(ra[tb*4+0],s4.x, scv)));
        s[tb*4+1] = fmaf(xa[tb*4+1],suv, fmaf(ya[tb*4+1],swv, fmaf(ra[tb*4+1],s4.y, scv)));
        s[tb*4+2] = fmaf(xa[tb*4+2],suv, fmaf(ya[tb*4+2],swv, fmaf(ra[tb*4+2],s4.z, scv)));
        s[tb*4+3] = fmaf(xa[tb*4+3],suv, fmaf(ya[tb*4+3],swv, fmaf(ra[tb*4+3],s4.w, scv)));
      }
      float m = s[0];
      #pragma unroll
      for (int t2 = 1; t2 < 20; t2++) m = fmaxf(m, s[t2]);
      float sum = 0;
      #pragma unroll
      for (int t2 = 0; t2 < 20; t2++) { float p = __expf(s[t2] - m); s[t2] = p; sum += p; }
      float inv = 1.0f / sum;
      float P = 0, Q = 0;
      #pragma unroll
      for (int t2 = 0; t2 < 20; t2++) { P = fmaf(s[t2], xa[t2], P); Q = fmaf(s[t2], ya[t2], Q); }
      P *= inv; Q *= inv;
      unsigned short* Zr = Z + (e*3 + w)*200;
      #pragma unroll
      for (int t2 = 0; t2 < 10; t2++) {
        unsigned int lo = f2b(s[2*t2]   * ra[2*t2]   * inv);
        unsigned int hi = f2b(s[2*t2+1] * ra[2*t2+1] * inv);
        *(unsigned int*)&Zr[h*20 + 2*t2] = lo | (hi << 16);
      }
      Zr[160 + h] = f2b(P);
      Zr[168 + h] = f2b(Q);
    }
  }
  // Prefetch OM fragments (no Z dependency -> in flight across b3)
  bf16x8 BfOM[2][6];
  #pragma unroll
  for (int nt = 0; nt < 2; nt++)
    #pragma unroll
    for (int kt = 0; kt < 6; kt++)
      BfOM[nt][kt] = *(const bf16x8*)(OMf + ((wv*2 + nt)*6 + kt)*512 + lane*8);
  __syncthreads();                                        // b3

  // ---- P3: GEMM1 attn_out = Z(48x192) @ OM^T, fused LN -> X bf16 ----
  {
    f32x4 acc[3][2];
    #pragma unroll
    for (int mt = 0; mt < 3; mt++)
      #pragma unroll
      for (int nt = 0; nt < 2; nt++) acc[mt][nt] = (f32x4){0.f,0.f,0.f,0.f};
    #pragma unroll
    for (int kt = 0; kt < 6; kt++) {
      bf16x8 Af[3];
      #pragma unroll
      for (int mt = 0; mt < 3; mt++)
        Af[mt] = *(const bf16x8*)(Z + (mt*16 + c)*200 + kt*32 + g*8);
      #pragma unroll
      for (int mt = 0; mt < 3; mt++)
        #pragma unroll
        for (int nt = 0; nt < 2; nt++)
          acc[mt][nt] = mfma16(Af[mt], BfOM[nt][kt], acc[mt][nt]);
    }
    // fragment-LN: add queries_n, column-group reduce for mean/var
    float p1[3][4], p2[3][4];
    #pragma unroll
    for (int mt = 0; mt < 3; mt++)
      #pragma unroll
      for (int j = 0; j < 4; j++) {
        int row = mt*16 + g*4 + j;
        int w = row % 3;
        float v0 = acc[mt][0][j] + QNl[w*128 + nb + c];
        float v1 = acc[mt][1][j] + QNl[w*128 + nb + 16 + c];
        acc[mt][0][j] = v0; acc[mt][1][j] = v1;
        p1[mt][j] = v0 + v1;
        p2[mt][j] = v0*v0 + v1*v1;
      }
    #pragma unroll
    for (int mt = 0; mt < 3; mt++)
      #pragma unroll
      for (int j = 0; j < 4; j++) {
        #pragma unroll
        for (int mk = 1; mk <= 8; mk <<= 1) {
          p1[mt][j] += __shfl_xor(p1[mt][j], mk, 64);
          p2[mt][j] += __shfl_xor(p2[mt][j], mk, 64);
        }
      }
    if (c < 4) {
      #pragma unroll
      for (int mt = 0; mt < 3; mt++) {
        float a = (c==0)?p1[mt][0]:(c==1)?p1[mt][1]:(c==2)?p1[mt][2]:p1[mt][3];
        float b = (c==0)?p2[mt][0]:(c==1)?p2[mt][1]:(c==2)?p2[mt][2]:p2[mt][3];
        int row = mt*16 + g*4 + c;
        *(float2*)&Pp[row*8 + wv*2] = make_float2(a, b);
      }
    }
    __syncthreads();                                      // b4: Pp ready, Z dead
    // X = LN'd x; m/sc recomputed per thread from Pp (broadcast reads)
    {
      float pg0 = pagl[nb + c],      pb0 = pabl[nb + c];
      float pg1 = pagl[nb + 16 + c], pb1 = pabl[nb + 16 + c];
      #pragma unroll
      for (int mt = 0; mt < 3; mt++)
        #pragma unroll
        for (int j = 0; j < 4; j++) {
          int row = mt*16 + g*4 + j;
          float4 a = *(const float4*)&Pp[row*8];
          float4 b = *(const float4*)&Pp[row*8 + 4];
          float s1 = a.x + a.z + b.x + b.z;
          float s2 = a.y + a.w + b.y + b.w;
          float m  = s1 * (1.0f/128.0f);
          float sc = rsqrtf(s2 * (1.0f/128.0f) - m*m + 1e-5f);
          X[row*136 + nb + c]      = f2b((acc[mt][0][j] - m)*sc*pg0 + pb0);
          X[row*136 + nb + 16 + c] = f2b((acc[mt][1][j] - m)*sc*pg1 + pb1);
        }
    }
  }
  // Prefetch W1 half 0 (no dependency -> in flight across b5)
  bf16x8 BfW1[2][4];
  #pragma unroll
  for (int nt = 0; nt < 2; nt++)
    #pragma unroll
    for (int kt = 0; kt < 4; kt++)
      BfW1[nt][kt] = *(const bf16x8*)(W1f + ((wv*2 + nt)*4 + kt)*512 + lane*8);
  __syncthreads();                                        // b5: X ready

  // ---- P5/P6: FFN in two K=128 halves sharing h1 (48x136 bf16) ----
  f32x4 acc2[3][2];
  #pragma unroll
  for (int mt = 0; mt < 3; mt++)
    #pragma unroll
    for (int nt = 0; nt < 2; nt++) acc2[mt][nt] = (f32x4){0.f,0.f,0.f,0.f};

  #pragma unroll
  for (int h = 0; h < 2; h++) {
    // P5: fc1 half -> relu -> h1 (BfW1 prefetched)
    {
      f32x4 acc[3][2];
      #pragma unroll
      for (int mt = 0; mt < 3; mt++)
        #pragma unroll
        for (int nt = 0; nt < 2; nt++) acc[mt][nt] = (f32x4){0.f,0.f,0.f,0.f};
      #pragma unroll
      for (int kt = 0; kt < 4; kt++) {
        bf16x8 Af[3];
        #pragma unroll
        for (int mt = 0; mt < 3; mt++)
          Af[mt] = *(const bf16x8*)(X + (mt*16 + c)*136 + kt*32 + g*8);
        #pragma unroll
        for (int mt = 0; mt < 3; mt++)
          #pragma unroll
          for (int nt = 0; nt < 2; nt++)
            acc[mt][nt] = mfma16(Af[mt], BfW1[nt][kt], acc[mt][nt]);
      }
      float bb0 = f1b[h*128 + nb + c];
      float bb1 = f1b[h*128 + nb + 16 + c];
      #pragma unroll
      for (int mt = 0; mt < 3; mt++)
        #pragma unroll
        for (int j = 0; j < 4; j++) {
          int row = mt*16 + g*4 + j;
          h1[row*136 + nb + c]      = f2b(fmaxf(acc[mt][0][j] + bb0, 0.0f));
          h1[row*136 + nb + 16 + c] = f2b(fmaxf(acc[mt][1][j] + bb1, 0.0f));
        }
    }
    // Prefetch W2 for this half (in flight across the h1-ready barrier)
    bf16x8 BfW2[2][4];
    #pragma unroll
    for (int nt = 0; nt < 2; nt++)
      #pragma unroll
      for (int kt = 0; kt < 4; kt++)
        BfW2[nt][kt] = *(const bf16x8*)(W2f + ((wv*2 + nt)*8 + h*4 + kt)*512 + lane*8);
    __syncthreads();                                      // b6 / b8: h1 ready
    // P6: fc2 partial over this K-half, accumulate into acc2
    #pragma unroll
    for (int kt = 0; kt < 4; kt++) {
      bf16x8 Af[3];
      #pragma unroll
      for (int mt = 0; mt < 3; mt++)
        Af[mt] = *(const bf16x8*)(h1 + (mt*16 + c)*136 + kt*32 + g*8);
      #pragma unroll
      for (int mt = 0; mt < 3; mt++)
        #pragma unroll
        for (int nt = 0; nt < 2; nt++)
          acc2[mt][nt] = mfma16(Af[mt], BfW2[nt][kt], acc2[mt][nt]);
    }
    if (h == 0) {
      // Prefetch W1 half 1 (in flight across the h1-rewrite barrier)
      #pragma unroll
      for (int nt = 0; nt < 2; nt++)
        #pragma unroll
        for (int kt = 0; kt < 4; kt++)
          BfW1[nt][kt] = *(const bf16x8*)(W1f + ((8 + wv*2 + nt)*4 + kt)*512 + lane*8);
      __syncthreads();                                    // b7 (h1 rewrite guard)
    }
  }

  // ---- P6b epilogue: h2+bias+residual -> fragment-LN -> head -> out ----
  {
    float bb0 = f2b_[nb + c];
    float bb1 = f2b_[nb + 16 + c];
    float p1[3][4], p2[3][4];
    #pragma unroll
    for (int mt = 0; mt < 3; mt++)
      #pragma unroll
      for (int j = 0; j < 4; j++) {
        int row = mt*16 + g*4 + j;
        float v0 = acc2[mt][0][j] + bb0 + b2f(X[row*136 + nb + c]);
        float v1 = acc2[mt][1][j] + bb1 + b2f(X[row*136 + nb + 16 + c]);
        acc2[mt][0][j] = v0; acc2[mt][1][j] = v1;
        p1[mt][j] = v0 + v1;
        p2[mt][j] = v0*v0 + v1*v1;
      }
    #pragma unroll
    for (int mt = 0; mt < 3; mt++)
      #pragma unroll
      for (int j = 0; j < 4; j++) {
        #pragma unroll
        for (int mk = 1; mk <= 8; mk <<= 1) {
          p1[mt][j] += __shfl_xor(p1[mt][j], mk, 64);
          p2[mt][j] += __shfl_xor(p2[mt][j], mk, 64);
        }
      }
    if (c < 4) {
      #pragma unroll
      for (int mt = 0; mt < 3; mt++) {
        float a = (c==0)?p1[mt][0]:(c==1)?p1[mt][1]:(c==2)?p1[mt][2]:p1[mt][3];
        float b = (c==0)?p2[mt][0]:(c==1)?p2[mt][1]:(c==2)?p2[mt][2]:p2[mt][3];
        int row = mt*16 + g*4 + c;
        *(float2*)&Pp2[row*8 + wv*2] = make_float2(a, b);
      }
    }
    __syncthreads();                                      // b9: Pp2 ready
    // m/sc per thread from Pp2 (broadcast); head partials; cross-wave Op
    {
      float fg0 = pfg[nb + c],        fb0 = pfb[nb + c];
      float fg1 = pfg[nb + 16 + c],   fb1 = pfb[nb + 16 + c];
      float hw00 = hw[nb + c],        hw01 = hw[nb + 16 + c];
      float hw10 = hw[128 + nb + c],  hw11 = hw[128 + nb + 16 + c];
      float o0[3][4], o1[3][4];
      #pragma unroll
      for (int mt = 0; mt < 3; mt++)
        #pragma unroll
        for (int j = 0; j < 4; j++) {
          int row = mt*16 + g*4 + j;
          float4 a = *(const float4*)&Pp2[row*8];
          float4 b = *(const float4*)&Pp2[row*8 + 4];
          float s1 = a.x + a.z + b.x + b.z;
          float s2 = a.y + a.w + b.y + b.w;
          float m  = s1 * (1.0f/128.0f);
          float sc = rsqrtf(s2 * (1.0f/128.0f) - m*m + 1e-5f);
          float x0 = (acc2[mt][0][j] - m)*sc*fg0 + fb0;
          float x1 = (acc2[mt][1][j] - m)*sc*fg1 + fb1;
          o0[mt][j] = x0*hw00 + x1*hw01;
          o1[mt][j] = x0*hw10 + x1*hw11;
        }
      #pragma unroll
      for (int mt = 0; mt < 3; mt++)
        #pragma unroll
        for (int j = 0; j < 4; j++) {
          #pragma unroll
          for (int mk = 1; mk <= 8; mk <<= 1) {
            o0[mt][j] += __shfl_xor(o0[mt][j], mk, 64);
            o1[mt][j] += __shfl_xor(o1[mt][j], mk, 64);
          }
        }
      if (c < 4) {
        #pragma unroll
        for (int mt = 0; mt < 3; mt++) {
          float a = (c==0)?o0[mt][0]:(c==1)?o0[mt][1]:(c==2)?o0[mt][2]:o0[mt][3];
          float b = (c==0)?o1[mt][0]:(c==1)?o1[mt][1]:(c==2)?o1[mt][2]:o1[mt][3];
          int row = mt*16 + g*4 + c;
          *(float2*)&Op[row*8 + wv*2] = make_float2(a, b);
        }
      }
    }
    __syncthreads();                                      // b10: Op ready
    if (tid < 48) {
      float4 a = *(const float4*)&Op[tid*8];
      float4 b = *(const float4*)&Op[tid*8 + 4];
      out[(wg*48 + tid)*2]     = a.x + a.z + b.x + b.z + hb[0];
      out[(wg*48 + tid)*2 + 1] = a.y + a.w + b.y + b.w + hb[1];
    }
  }
}

// ---------------------------------------------------------------------------
extern "C" void kernel_launch(void* const* d_in, const int* in_sizes, int n_in,
                              void* d_out, int out_size, void* d_ws, size_t ws_size,
                              hipStream_t stream) {
  const float* tl       = (const float*)d_in[0];
  const float* tr       = (const float*)d_in[1];
  const float* coord_w  = (const float*)d_in[2];
  const float* coord_b  = (const float*)d_in[3];
  const float* pos_emb  = (const float*)d_in[4];
  const float* side_emb = (const float*)d_in[5];
  const float* query_emb= (const float*)d_in[6];
  const float* tln_g    = (const float*)d_in[7];
  const float* tln_b    = (const float*)d_in[8];
  const float* qln_g    = (const float*)d_in[9];
  const float* qln_b    = (const float*)d_in[10];
  const float* ipw      = (const float*)d_in[11];
  const float* ipb      = (const float*)d_in[12];
  const float* opw      = (const float*)d_in[13];
  const float* opb      = (const float*)d_in[14];
  const float* f1w      = (const float*)d_in[15];
  const float* f1b      = (const float*)d_in[16];
  const float* f2w      = (const float*)d_in[17];
  const float* f2b2     = (const float*)d_in[18];
  const float* pag      = (const float*)d_in[19];
  const float* pab      = (const float*)d_in[20];
  const float* pfg      = (const float*)d_in[21];
  const float* pfb      = (const float*)d_in[22];
  const float* hw       = (const float*)d_in[23];
  const float* hb       = (const float*)d_in[24];
  char* ws = (char*)d_ws;

  k_prep<<<53, 128, 0, stream>>>(coord_w, coord_b, pos_emb, side_emb, query_emb,
                                 tln_g, tln_b, qln_g, qln_b, ipw, ipb,
                                 opw, opb, f1w, f2w, ws);
  k_main<<<32768 / GE, 256, 0, stream>>>(tl, tr, f1b, f2b2, pag, pab, pfg, pfb,
                                         hw, hb, ws, (float*)d_out);
}